// Round 1
// baseline (214.753 us; speedup 1.0000x reference)
//
#include <hip/hip_runtime.h>

// AttnBlock: GN(32) -> 1x1 qkv -> full attention (B=2,C=512,N=4096) -> 1x1 proj -> +x
// R8: 256^2-tile fp8 GEMM template (gemm256) with 4-slot LDS ring + counted vmcnt
// (never 0 mid-loop) + raw s_barrier + setprio around MFMA clusters (T3/T4/T5),
// 16B-slot XOR swizzle staged via pre-swizzled global source (T2). Used for QKV,
// S (deferred-softmax epilogue), PV (split-K=4). proj stays on 128^2 kernel
// (grid too small for 256^2). Accumulation order bit-identical to R7.

typedef unsigned short u16;
typedef unsigned int u32;
typedef unsigned char u8;
typedef float f32x4 __attribute__((ext_vector_type(4)));

#define NPOS 4096
#define CCH 512

__device__ __forceinline__ u16 f2bf(float f) {
  u32 u = __builtin_bit_cast(u32, f);
  u += 0x7fffu + ((u >> 16) & 1u);
  return (u16)(u >> 16);
}
__device__ __forceinline__ float bf2f(u16 h) {
  u32 u = ((u32)h) << 16;
  return __builtin_bit_cast(float, u);
}
__device__ __forceinline__ u8 f2fp8(float f) {
  u32 pk = __builtin_amdgcn_cvt_pk_fp8_f32(f, f, 0, false);
  return (u8)(pk & 0xff);
}

__device__ __forceinline__ void load16_lds8(const u8* g, u8* l) {
  __builtin_amdgcn_global_load_lds(
      (const __attribute__((address_space(1))) void*)g,
      (__attribute__((address_space(3))) void*)l, 16, 0, 0);
}

// ---------------- GroupNorm partial stats ----------------
__global__ __launch_bounds__(256) void gn_stats_part(const float* __restrict__ x,
                                                     float2* __restrict__ part) {
  int id = blockIdx.x;  // (b*32+g)*4+p, each 16384 contiguous floats
  const float4* p = (const float4*)(x + (size_t)id * 16384);
  float s = 0.f, s2 = 0.f;
  for (int i = threadIdx.x; i < 4096; i += 256) {
    float4 u = p[i];
    s += u.x + u.y + u.z + u.w;
    s2 += u.x * u.x + u.y * u.y + u.z * u.z + u.w * u.w;
  }
  for (int o = 32; o; o >>= 1) {
    s += __shfl_xor(s, o);
    s2 += __shfl_xor(s2, o);
  }
  __shared__ float rs[4], rq[4];
  int lane = threadIdx.x & 63, w = threadIdx.x >> 6;
  if (lane == 0) { rs[w] = s; rq[w] = s2; }
  __syncthreads();
  if (threadIdx.x == 0)
    part[id] = make_float2(rs[0] + rs[1] + rs[2] + rs[3], rq[0] + rq[1] + rq[2] + rq[3]);
}

// normalize + transpose: x[b][c][n] (f32) -> h8[b][n][c] (fp8); stats from pstats inline
__global__ __launch_bounds__(256) void gn_apply8(const float* __restrict__ x,
                                                 const float* __restrict__ gnw,
                                                 const float* __restrict__ gnb,
                                                 const float2* __restrict__ pstats,
                                                 u8* __restrict__ h8) {
  int b = blockIdx.z, c0 = blockIdx.y * 64, n0 = blockIdx.x * 64;
  __shared__ u8 lt[64][80];
  const float* xb = x + (size_t)b * CCH * NPOS;
  int tid = threadIdx.x;
#pragma unroll
  for (int it = 0; it < 4; ++it) {
    int ci = (tid >> 4) + it * 16;
    int nj = (tid & 15) * 4;
    int c = c0 + ci;
    float4 v = *(const float4*)&xb[(size_t)c * NPOS + n0 + nj];
    const float2* pp = pstats + ((size_t)b * 32 + (c >> 4)) * 4;
    float s = pp[0].x + pp[1].x + pp[2].x + pp[3].x;
    float s2 = pp[0].y + pp[1].y + pp[2].y + pp[3].y;
    float mu = s * (1.f / 65536.f);
    float var = s2 * (1.f / 65536.f) - mu * mu;
    float rst = rsqrtf(var + 1e-6f);
    float w = gnw[c] * rst;
    float bb = gnb[c] - mu * w;
    lt[nj + 0][ci] = f2fp8(v.x * w + bb);
    lt[nj + 1][ci] = f2fp8(v.y * w + bb);
    lt[nj + 2][ci] = f2fp8(v.z * w + bb);
    lt[nj + 3][ci] = f2fp8(v.w * w + bb);
  }
  __syncthreads();
  int ni = tid >> 2, cj = (tid & 3) * 16;
  uint4 o = *(const uint4*)&lt[ni][cj];
  *(uint4*)&h8[((size_t)b * NPOS + n0 + ni) * CCH + c0 + cj] = o;
}

// -------- weight f32 -> fp8 (wq|wk|wv|wp contiguous) + qkv bias pack --------
__global__ __launch_bounds__(256) void wconv8(const float* __restrict__ w0,
                                              const float* __restrict__ w1,
                                              const float* __restrict__ w2,
                                              const float* __restrict__ w3,
                                              u8* __restrict__ dst,
                                              const float* __restrict__ bq,
                                              const float* __restrict__ bk,
                                              const float* __restrict__ bv,
                                              float* __restrict__ bqkv) {
  int which = blockIdx.y;
  int bx = blockIdx.x;
  int t = threadIdx.x;
  if (bx == 256) {
    if (which < 3) {
      const float* bsrc = which == 0 ? bq : which == 1 ? bk : bv;
      bqkv[which * 512 + t] = bsrc[t];
      bqkv[which * 512 + 256 + t] = bsrc[256 + t];
    }
    return;
  }
  const float* src = which == 0 ? w0 : which == 1 ? w1 : which == 2 ? w2 : w3;
  u8* d = dst + (size_t)which * (CCH * CCH);
  int i = bx * 256 + t;
  float4 v = ((const float4*)src)[i];
  u32 pk = __builtin_amdgcn_cvt_pk_fp8_f32(v.x, v.y, 0, false);
  pk = __builtin_amdgcn_cvt_pk_fp8_f32(v.z, v.w, pk, true);
  ((u32*)d)[i] = pk;
}

// ------- legacy 128^2 fp8 GEMM (kept for proj: EPI 1 = f32 alpha*v+bias[m]+resid) -------
template <int EPI, bool SWIZ>
__global__ __launch_bounds__(256, 4) void gemm_f8(const u8* __restrict__ A,
                                                  const u8* __restrict__ Bm,
                                                  void* __restrict__ Cv,
                                                  const float* __restrict__ bias,
                                                  const float* __restrict__ resid,
                                                  float* __restrict__ lpart,
                                                  float alpha, int K,
                                                  int lda, int ldb, int ldc,
                                                  long sA, long sB, long sC, long sR) {
  const int b = blockIdx.z;
  int bx = blockIdx.x, by = blockIdx.y;
  if (SWIZ) {
    int id = by * gridDim.x + bx;
    int g = id >> 8;
    int w = id & 255;
    bx = (g << 3) | (w & 7);
    by = w >> 3;
  }
  A += (size_t)b * sA;
  Bm += (size_t)b * sB;
  const int m0 = by * 128, n0 = bx * 128;
  __shared__ u8 sAt[128 * 128];
  __shared__ u8 sBt[128 * 128];
  const int tid = threadIdx.x, wave = tid >> 6, lane = tid & 63;
  const int lrow = lane & 15, kch = lane >> 4;
  const int wm = (wave >> 1) * 64, wn = (wave & 1) * 64;
  const int srow = lane >> 3;
  const int sseg = ((lane & 7) ^ srow) * 16;
  f32x4 acc[4][4] = {};

  for (int k0 = 0; k0 < K; k0 += 128) {
#pragma unroll
    for (int r = 0; r < 4; ++r) {
      int ch = wave * 4 + r;
      load16_lds8(A + (size_t)(m0 + ch * 8 + srow) * lda + (k0 + sseg), sAt + ch * 1024);
      load16_lds8(Bm + (size_t)(n0 + ch * 8 + srow) * ldb + (k0 + sseg), sBt + ch * 1024);
    }
    __syncthreads();
#pragma unroll
    for (int kk = 0; kk < 4; ++kk) {
      const int seg16 = kk * 2 + (kch >> 1);
      const int sub = (kch & 1) * 8;
      long af[4], bf[4];
#pragma unroll
      for (int i = 0; i < 4; ++i) {
        int ra = wm + i * 16 + lrow;
        af[i] = *(const long*)(sAt + ra * 128 + (seg16 ^ (ra & 7)) * 16 + sub);
        int rb = wn + i * 16 + lrow;
        bf[i] = *(const long*)(sBt + rb * 128 + (seg16 ^ (rb & 7)) * 16 + sub);
      }
#pragma unroll
      for (int i = 0; i < 4; ++i)
#pragma unroll
        for (int j = 0; j < 4; ++j)
          acc[i][j] =
              __builtin_amdgcn_mfma_f32_16x16x32_fp8_fp8(af[i], bf[j], acc[i][j], 0, 0, 0);
    }
    __syncthreads();
  }

  const int col = lane & 15, rbase = (lane >> 4) * 4;
  const size_t cb = (size_t)b * sC;
#pragma unroll
  for (int i = 0; i < 4; ++i) {
    int mrow = m0 + wm + i * 16 + rbase;
#pragma unroll
    for (int j = 0; j < 4; ++j) {
      int ncol = n0 + wn + j * 16 + col;
      float bcol = (EPI == 0) ? bias[ncol] : 0.f;
#pragma unroll
      for (int r = 0; r < 4; ++r) {
        int m = mrow + r;
        size_t ci = cb + (size_t)m * ldc + ncol;
        float v = acc[i][j][r];
        if (EPI == 0) {
          ((u8*)Cv)[ci] = f2fp8(v + bcol);
        } else {
          v = v * alpha + bias[m] + resid[(size_t)b * sR + (size_t)m * ldc + ncol];
          ((float*)Cv)[ci] = v;
        }
      }
    }
  }
}

// ======================= 256^2 fp8 GEMM, 4-slot ring, counted vmcnt =======================
// BM=BN=256, BK=64, 512 thr / 8 waves (2Mx4N), per-wave 128x64, LDS 4*(16K A+16K B)=128KB.
// Prefetch 3 tiles ahead; per K-tile: vmcnt(8)+s_barrier (NEVER vmcnt(0) mid-loop),
// issue tile t+3 into slot (t+3)&3 (== slot (t-1)&3, whose reads ended at this barrier).
// LDS layout: row-major [256][64] with 16B-slot swizzle slot^=(row>>1)&3, applied on the
// GLOBAL source (linear lds dest) and mirrored on reads -> <=2-way bank conflict (free).
// EPI: 0 = fp8(v+bias[ncol]) store; 2 = U8=fp8(4*exp(clamp(alpha*v))) + lpart row sums;
//      3 = bf16 split-K partial store + (bx==0) lpart->lsum fold.
template <int EPI, int NT>
__global__ __launch_bounds__(512, 2) void gemm256(
    const u8* __restrict__ A, const u8* __restrict__ Bm, void* __restrict__ Cv,
    const float* __restrict__ bias, float* __restrict__ lpart,
    const float* __restrict__ lpart_in, float* __restrict__ lsum,
    float alpha, long lda, long ldb, long ldc, long sA, long sB, long sC) {
  __shared__ u8 LDS[4][32768];

  // bijective XCD remap (nwg per z divisible by 8 for all uses)
  int lin = blockIdx.x + gridDim.x * blockIdx.y;
  const int nq = (gridDim.x * gridDim.y) >> 3;
  lin = (lin & 7) * nq + (lin >> 3);
  const int bx = lin % gridDim.x, by = lin / gridDim.x;
  const int m0 = by * 256, n0 = bx * 256;

  int b;
  const u8 *Ab, *Bb;
  if constexpr (EPI == 3) {
    b = blockIdx.z >> 2;
    const int slice = blockIdx.z & 3;
    Ab = A + (size_t)b * sA + (size_t)slice * 1024;
    Bb = Bm + (size_t)b * sB + (size_t)slice * 1024;
  } else {
    b = blockIdx.z;
    Ab = A + (size_t)b * sA;
    Bb = Bm + (size_t)b * sB;
  }

  const int tid = threadIdx.x, wave = tid >> 6, lane = tid & 63;
  const int lrow = lane & 15, kch = lane >> 4;
  const int wr = wave >> 2, wc = wave & 3;

  // --- staging addresses: thread covers row srow (sweep0) / srow+128 (sweep1), slot lane&3
  const int srow = wave * 16 + (lane >> 2);
  const int ssw = ((lane & 3) ^ ((srow >> 1) & 3)) * 16;  // same for srow+128 (128>>1 ≡ 0 mod 4)
  const u8* gA = Ab + (size_t)(m0 + srow) * lda + ssw;
  const u8* gB = Bb + (size_t)(n0 + srow) * ldb + ssw;
  u8* lA = &LDS[0][0] + wave * 1024;  // wave-uniform; +slot*32768, +8192 sweep1, +16384 B

  // --- compute-side fragment offsets (g=0; g=1 toggles addr bit 5: slot ^= 2)
  const int swz = (lrow >> 1) & 3;
  const int cst = (kch & 1) * 8 + (((kch >> 1) ^ swz) << 4);
  int aoff[8], boff[4];
#pragma unroll
  for (int i = 0; i < 8; ++i) aoff[i] = (wr * 128 + i * 16 + lrow) * 64 + cst;
#pragma unroll
  for (int j = 0; j < 4; ++j) boff[j] = (wc * 64 + j * 16 + lrow) * 64 + cst + 16384;

  f32x4 acc[8][4] = {};

  auto STAGE = [&](int t) {  // 4 vm-ops per wave per tile
    const int sl = (t & 3) * 32768;
    const long k0 = (long)t * 64;
    load16_lds8(gA + k0, lA + sl);
    load16_lds8(gB + k0, lA + sl + 16384);
    load16_lds8(gA + 128 * lda + k0, lA + sl + 8192);
    load16_lds8(gB + 128 * ldb + k0, lA + sl + 24576);
  };

  STAGE(0);
  STAGE(1);
  STAGE(2);

  for (int t = 0; t < NT; ++t) {
    // own tile-t loads retired (3 tiles = 12 ops max in flight after prologue/steady state)
    if (t < NT - 2)
      asm volatile("s_waitcnt vmcnt(8)" ::: "memory");
    else if (t == NT - 2)
      asm volatile("s_waitcnt vmcnt(4)" ::: "memory");
    else
      asm volatile("s_waitcnt vmcnt(0)" ::: "memory");
    asm volatile("s_barrier" ::: "memory");  // all waves' tile-t data visible; slot (t-1)&3 free
    if (t + 3 < NT) STAGE(t + 3);
    const u8* sb = &LDS[t & 3][0];
#pragma unroll
    for (int g = 0; g < 2; ++g) {
      long a_[8], b_[4];
#pragma unroll
      for (int i = 0; i < 8; ++i) a_[i] = *(const long*)(sb + (aoff[i] ^ (g << 5)));
#pragma unroll
      for (int j = 0; j < 4; ++j) b_[j] = *(const long*)(sb + (boff[j] ^ (g << 5)));
      __builtin_amdgcn_s_setprio(1);
#pragma unroll
      for (int i = 0; i < 8; ++i)
#pragma unroll
        for (int j = 0; j < 4; ++j)
          acc[i][j] =
              __builtin_amdgcn_mfma_f32_16x16x32_fp8_fp8(a_[i], b_[j], acc[i][j], 0, 0, 0);
      __builtin_amdgcn_s_setprio(0);
    }
  }

  const int col = lane & 15, rbase = kch * 4;
  if constexpr (EPI == 0) {
    u8* C = (u8*)Cv + (size_t)b * sC;
#pragma unroll
    for (int i = 0; i < 8; ++i) {
      const int mrow = m0 + wr * 128 + i * 16 + rbase;
#pragma unroll
      for (int j = 0; j < 4; ++j) {
        const int ncol = n0 + wc * 64 + j * 16 + col;
        const float bc = bias[ncol];
#pragma unroll
        for (int r = 0; r < 4; ++r)
          C[(size_t)(mrow + r) * ldc + ncol] = f2fp8(acc[i][j][r] + bc);
      }
    }
  } else if constexpr (EPI == 2) {
    u8* C = (u8*)Cv + (size_t)b * sC;
#pragma unroll
    for (int i = 0; i < 8; ++i) {
      const int mrow = m0 + wr * 128 + i * 16 + rbase;
      float rsum[4] = {0.f, 0.f, 0.f, 0.f};
#pragma unroll
      for (int j = 0; j < 4; ++j) {
        const int ncol = n0 + wc * 64 + j * 16 + col;
#pragma unroll
        for (int r = 0; r < 4; ++r) {
          float s = fminf(fmaxf(acc[i][j][r] * alpha, -10.f), 4.5f);
          float e = __expf(s);
          rsum[r] += e;
          C[(size_t)(mrow + r) * ldc + ncol] = f2fp8(4.f * e);
        }
      }
#pragma unroll
      for (int r = 0; r < 4; ++r) {
        float v = rsum[r];
        v += __shfl_xor(v, 1);
        v += __shfl_xor(v, 2);
        v += __shfl_xor(v, 4);
        v += __shfl_xor(v, 8);
        if (col == 0)
          lpart[((size_t)b * NPOS + mrow + r) * 64 + bx * 4 + wc] = v;
      }
    }
  } else {  // EPI == 3: PV split-K partials (bf16) + lsum fold
    const int slice = blockIdx.z & 3;
    u16* dst = (u16*)Cv + (size_t)slice * ((size_t)2 * NPOS * CCH) +
               (size_t)b * ((size_t)NPOS * CCH);
#pragma unroll
    for (int i = 0; i < 8; ++i) {
      const int mrow = m0 + wr * 128 + i * 16 + rbase;
#pragma unroll
      for (int j = 0; j < 4; ++j) {
        const int ncol = n0 + wc * 64 + j * 16 + col;
#pragma unroll
        for (int r = 0; r < 4; ++r)
          dst[(size_t)(mrow + r) * CCH + ncol] = f2bf(acc[i][j][r]);
      }
    }
    if (bx == 0 && tid < 256) {
      const float* lp = lpart_in + ((size_t)b * NPOS + m0 + tid) * 64;
      float s = 0.f;
#pragma unroll
      for (int c = 0; c < 64; ++c) s += lp[c];
      lsum[(size_t)b * NPOS + m0 + tid] = s;
    }
  }
}

// ------- merge 4 bf16 split-K partials, divide by lsum -> o8 = fp8(32*o) ------
__global__ __launch_bounds__(256) void merge_pv8(const u16* __restrict__ part,
                                                 const float* __restrict__ lsum,
                                                 u8* __restrict__ dst) {
  const long sl = 4194304;
  int i = blockIdx.x * 256 + threadIdx.x;  // 8 elems (one q, 8 d's) per thread
  long e0 = (long)i * 8;
  int q = (int)((e0 >> 9) & 4095);
  int b = (int)(e0 >> 21);
  // o = sum(parts)/(4*lsum); store 32*o -> factor 8/lsum
  float inv = 8.f / lsum[(size_t)b * NPOS + q];
  uint4 a = ((const uint4*)part)[i];
  uint4 bb = ((const uint4*)(part + sl))[i];
  uint4 c = ((const uint4*)(part + 2 * sl))[i];
  uint4 d = ((const uint4*)(part + 3 * sl))[i];
  u32 wa[4] = {a.x, a.y, a.z, a.w}, wb_[4] = {bb.x, bb.y, bb.z, bb.w};
  u32 wc[4] = {c.x, c.y, c.z, c.w}, wd[4] = {d.x, d.y, d.z, d.w};
  float v[8];
#pragma unroll
  for (int j = 0; j < 4; ++j) {
    v[2 * j] = (bf2f((u16)(wa[j] & 0xffff)) + bf2f((u16)(wb_[j] & 0xffff)) +
                bf2f((u16)(wc[j] & 0xffff)) + bf2f((u16)(wd[j] & 0xffff))) * inv;
    v[2 * j + 1] = (bf2f((u16)(wa[j] >> 16)) + bf2f((u16)(wb_[j] >> 16)) +
                    bf2f((u16)(wc[j] >> 16)) + bf2f((u16)(wd[j] >> 16))) * inv;
  }
  uint2 o;
  u32 p0 = __builtin_amdgcn_cvt_pk_fp8_f32(v[0], v[1], 0, false);
  p0 = __builtin_amdgcn_cvt_pk_fp8_f32(v[2], v[3], p0, true);
  u32 p1 = __builtin_amdgcn_cvt_pk_fp8_f32(v[4], v[5], 0, false);
  p1 = __builtin_amdgcn_cvt_pk_fp8_f32(v[6], v[7], p1, true);
  o.x = p0;
  o.y = p1;
  ((uint2*)dst)[i] = o;
}

// ------- transpose fp8: src[b][4096][1536] v-cols -> dst[b][512][4096] -------
__global__ __launch_bounds__(256) void transpose_v8(const u8* __restrict__ src,
                                                    u8* __restrict__ dst, int srcld) {
  int b = blockIdx.z, n0 = blockIdx.x * 64, d0 = blockIdx.y * 64;
  __shared__ u8 lt[64][80];
  const u8* s = src + (size_t)b * NPOS * srcld;
  u8* d = dst + (size_t)b * CCH * NPOS;
  int t = threadIdx.x;
  {
    int r = t >> 2, c16 = (t & 3) * 16;
    uint4 v = *(const uint4*)&s[(size_t)(n0 + r) * srcld + d0 + c16];
    *(uint4*)&lt[r][c16] = v;
  }
  __syncthreads();
  {
    int dr = t >> 2, c16 = (t & 3) * 16;
    u8 tmp[16];
#pragma unroll
    for (int j = 0; j < 16; ++j) tmp[j] = lt[c16 + j][dr];
    *(uint4*)&d[(size_t)(d0 + dr) * NPOS + n0 + c16] = *(uint4*)tmp;
  }
}

extern "C" void kernel_launch(void* const* d_in, const int* in_sizes, int n_in,
                              void* d_out, int out_size, void* d_ws, size_t ws_size,
                              hipStream_t stream) {
  const float* x = (const float*)d_in[0];
  const float* gnw = (const float*)d_in[1];
  const float* gnb = (const float*)d_in[2];
  const float* wq = (const float*)d_in[3];
  const float* bq = (const float*)d_in[4];
  const float* wk = (const float*)d_in[5];
  const float* bk = (const float*)d_in[6];
  const float* wv = (const float*)d_in[7];
  const float* bv = (const float*)d_in[8];
  const float* wp = (const float*)d_in[9];
  const float* bp = (const float*)d_in[10];
  float* out = (float*)d_out;

  char* ws = (char*)d_ws;
  size_t off = 0;
  auto alloc = [&](size_t bytes) {
    void* p = ws + off;
    off += (bytes + 1023) & ~(size_t)1023;
    return p;
  };
  float2* pstats = (float2*)alloc(256 * sizeof(float2));
  u8* w8 = (u8*)alloc((size_t)4 * CCH * CCH);          // 1MB wq|wk|wv|wp fp8
  u8* wp8 = w8 + 3 * CCH * CCH;
  float* bqkv = (float*)alloc(1536 * sizeof(float));
  u8* h8 = (u8*)alloc((size_t)2 * NPOS * CCH);         // 4MB [b][n][c]
  u8* qkv8 = (u8*)alloc((size_t)2 * NPOS * 1536);      // 12MB [b][n][q|k|v]
  u8* v8 = (u8*)alloc((size_t)2 * CCH * NPOS);         // 4MB [b][d][n]
  u8* U8 = (u8*)alloc((size_t)2 * NPOS * NPOS);        // 32MB [b][nq][nk] = 4*exp
  float* lpart = (float*)alloc((size_t)2 * NPOS * 64 * 4);  // 2MB [b][q][64]
  float* lsum = (float*)alloc((size_t)2 * NPOS * 4);        // 32KB [b][q]
  u16* part_pv = (u16*)alloc((size_t)4 * 2 * NPOS * CCH * 2);  // 32MB bf16 partials
  u8* o8 = (u8*)alloc((size_t)2 * NPOS * CCH);         // 4MB [b][n][c] = 32*o

  const long sHC8 = (long)NPOS * CCH;
  const long sQKV8 = (long)NPOS * 1536;
  const long sSS8 = (long)NPOS * NPOS;
  const long sOUT = (long)CCH * NPOS;
  const float scale = 0.044194173824159216f;  // 512^-0.5

  gn_stats_part<<<256, 256, 0, stream>>>(x, pstats);
  gn_apply8<<<dim3(64, 8, 2), 256, 0, stream>>>(x, gnw, gnb, pstats, h8);
  wconv8<<<dim3(257, 4), 256, 0, stream>>>(wq, wk, wv, wp, w8, bq, bk, bv, bqkv);
  // fused qkv: qkv8[b][n][0:1536] = fp8(h8 . (wq|wk|wv)^T + bias)   (256^2 ring)
  gemm256<0, 8><<<dim3(6, 16, 2), 512, 0, stream>>>(
      h8, w8, qkv8, bqkv, nullptr, nullptr, nullptr, 1.f,
      CCH, CCH, 1536, sHC8, 0, sQKV8);
  // v8[b][d][n] = transpose of qkv8 v-columns
  transpose_v8<<<dim3(64, 8, 2), 256, 0, stream>>>(qkv8 + 1024, v8, 1536);
  // U8 = fp8(4*exp(clamp(scale * q.k^T))) + lpart row-sums   (256^2 ring)
  gemm256<2, 8><<<dim3(16, 16, 2), 512, 0, stream>>>(
      qkv8, qkv8 + 512, U8, nullptr, lpart, nullptr, nullptr, scale,
      1536, 1536, NPOS, sQKV8, sQKV8, sSS8);
  // PV fp8 split-K=4 into bf16 partials; bx==0 folds lpart->lsum   (256^2 ring)
  gemm256<3, 16><<<dim3(2, 16, 8), 512, 0, stream>>>(
      U8, v8, part_pv, nullptr, nullptr, lpart, lsum, 1.f,
      NPOS, NPOS, CCH, (long)NPOS * NPOS, (long)CCH * NPOS, 0);
  // merge partials, normalize by lsum -> o8 = fp8(32*o)
  merge_pv8<<<2048, 256, 0, stream>>>(part_pv, lsum, o8);
  // proj: out[b][d][n] = (wp . o8^T)/32 + bp + x   (legacy 128^2, grid fills 256 CUs)
  gemm_f8<1, false><<<dim3(32, 4, 2), 256, 0, stream>>>(
      wp8, o8, out, bp, x, nullptr, 1.f / 32.f, CCH, CCH, CCH, NPOS,
      0, sHC8, sOUT, sOUT);
}